// Round 5
// baseline (99803.412 us; speedup 1.0000x reference)
//
#include <hip/hip_runtime.h>
#include <hip/hip_bf16.h>
#include <stdint.h>

#define T_STEPS 32768
#define HID 1024
#define FIN 256
#define NB 32            // scan blocks
#define RPB (HID / NB)   // rows per block = 32
#define RPW 8            // rows per compute wave (4 compute waves/block)
#define WORDS (HID / 2)  // packed 8B words per h vector = 512

typedef unsigned long long ull;

// ---------------- Phase 1: xw[t][h] = sum_k x[t][k] * wih[h][k] ----------------
__global__ __launch_bounds__(256) void gemm_xw(const float* __restrict__ x,
                                               const float* __restrict__ wih,
                                               float* __restrict__ out) {
    __shared__ float As[32][132];
    __shared__ float Bs[32][132];
    const int tid = threadIdx.x;
    const int m0 = blockIdx.y * 128;
    const int n0 = blockIdx.x * 128;
    const int tm = tid >> 4, tn = tid & 15;
    const int lr = tid >> 1, lc = (tid & 1) * 16;

    float acc[8][8];
#pragma unroll
    for (int i = 0; i < 8; ++i)
#pragma unroll
        for (int j = 0; j < 8; ++j) acc[i][j] = 0.f;

    for (int kk = 0; kk < FIN; kk += 32) {
#pragma unroll
        for (int u = 0; u < 4; ++u) {
            float4 av = *reinterpret_cast<const float4*>(
                &x[(size_t)(m0 + lr) * FIN + kk + lc + 4 * u]);
            float4 bv = *reinterpret_cast<const float4*>(
                &wih[(size_t)(n0 + lr) * FIN + kk + lc + 4 * u]);
            As[lc + 4 * u + 0][lr] = av.x;
            As[lc + 4 * u + 1][lr] = av.y;
            As[lc + 4 * u + 2][lr] = av.z;
            As[lc + 4 * u + 3][lr] = av.w;
            Bs[lc + 4 * u + 0][lr] = bv.x;
            Bs[lc + 4 * u + 1][lr] = bv.y;
            Bs[lc + 4 * u + 2][lr] = bv.z;
            Bs[lc + 4 * u + 3][lr] = bv.w;
        }
        __syncthreads();
#pragma unroll
        for (int k = 0; k < 32; ++k) {
            const float4* Ak = reinterpret_cast<const float4*>(&As[k][0]);
            const float4* Bk = reinterpret_cast<const float4*>(&Bs[k][0]);
            float4 a0 = Ak[tm * 2], a1 = Ak[tm * 2 + 1];
            float4 b0 = Bk[tn * 2], b1 = Bk[tn * 2 + 1];
            float a[8] = {a0.x, a0.y, a0.z, a0.w, a1.x, a1.y, a1.z, a1.w};
            float b[8] = {b0.x, b0.y, b0.z, b0.w, b1.x, b1.y, b1.z, b1.w};
#pragma unroll
            for (int i = 0; i < 8; ++i)
#pragma unroll
                for (int j = 0; j < 8; ++j) acc[i][j] = fmaf(a[i], b[j], acc[i][j]);
        }
        __syncthreads();
    }
#pragma unroll
    for (int i = 0; i < 8; ++i) {
        float4 o0 = make_float4(acc[i][0], acc[i][1], acc[i][2], acc[i][3]);
        float4 o1 = make_float4(acc[i][4], acc[i][5], acc[i][6], acc[i][7]);
        float* op = &out[(size_t)(m0 + tm * 8 + i) * HID + n0 + tn * 8];
        *reinterpret_cast<float4*>(op) = o0;
        *reinterpret_cast<float4*>(op + 4) = o1;
    }
}

// ---------------- Phase 2: persistent serial scan ----------------
__device__ __forceinline__ float fast_tanh(float x) {
    float cx = fminf(fmaxf(x, -16.f), 16.f);
    float e = __builtin_amdgcn_exp2f(cx * 2.8853900817779268f);
    return (e - 1.f) * __builtin_amdgcn_rcpf(e + 1.f);
}

__device__ __forceinline__ void poll8(const ull* __restrict__ src, int lane,
                                      ull (&v)[8]) {
#pragma unroll
    for (int i = 0; i < 8; ++i)
        v[i] = __hip_atomic_load(src + lane + 64 * i, __ATOMIC_RELAXED,
                                 __HIP_MEMORY_SCOPE_AGENT);
}

__device__ __forceinline__ bool check8(const ull (&v)[8], unsigned expb) {
    unsigned d = 0;
#pragma unroll
    for (int i = 0; i < 8; ++i) d |= (((unsigned)v[i]) ^ expb) & 0xFFu;
    return d == 0;
}

// Transport: h packed as 512 x 8B words (two f32); even element's low mantissa
// byte = tag (t+1)&0xFF (perturbation ~2^-16 rel; generations differ by 2 mod
// 256 -> never collide). Double-buffered by parity, relaxed agent atomics.
//
// Block = 5 waves. wave0 = dedicated poller: 3-deep pipelined free-spin poll
// (in-order vmcnt: checking oldest batch leaves newer in flight -> sampling
// period ~ RT/3), publish to LDS, release-store seq=t, immediately poll t+1.
// Waves 1-4: spin on seq (acquire) with a live dummy-FMA chain (keeps VALU
// busy -> holds boost clocks; no barrier sleep), then matvec.
// LDS dbuf reuse safe: poller overwrites hshw[t&1] only after all 512 global
// tags==t, which requires this block's h_t stores, which its compute waves
// issue after their last read of hshw[t&1] (step t-2).
__global__ __launch_bounds__(320, 1) void scan_rnn(
    const float* __restrict__ whh, const float* __restrict__ wgt,
    const float* __restrict__ bih, const float* __restrict__ bhh,
    const float* __restrict__ bb, float* __restrict__ out,
    ull* __restrict__ hbuf) {
    __shared__ ull hshw[2][WORDS];
    __shared__ int seq;
    const int lane = threadIdx.x & 63;
    const int wv = threadIdx.x >> 6;

    if (threadIdx.x == 0)
        __hip_atomic_store(&seq, -1, __ATOMIC_RELAXED,
                           __HIP_MEMORY_SCOPE_WORKGROUP);
    __syncthreads();

    if (wv == 0) {
        // ---- dedicated poller ----
        __builtin_amdgcn_s_setprio(1);
        for (int t = 0; t < T_STEPS; ++t) {
            const ull* src = hbuf + (size_t)(t & 1) * WORDS;
            const unsigned expb = (unsigned)t & 0xFFu;
            ull va[8], vb[8], vc[8];
            int hit = 0;
            poll8(src, lane, va);
            poll8(src, lane, vb);
            for (;;) {
                poll8(src, lane, vc);
                if (check8(va, expb)) { hit = 0; break; }
                poll8(src, lane, va);
                if (check8(vb, expb)) { hit = 1; break; }
                poll8(src, lane, vb);
                if (check8(vc, expb)) { hit = 2; break; }
            }
            if (hit == 0) {
#pragma unroll
                for (int i = 0; i < 8; ++i) hshw[t & 1][lane + 64 * i] = va[i];
            } else if (hit == 1) {
#pragma unroll
                for (int i = 0; i < 8; ++i) hshw[t & 1][lane + 64 * i] = vb[i];
            } else {
#pragma unroll
                for (int i = 0; i < 8; ++i) hshw[t & 1][lane + 64 * i] = vc[i];
            }
            if (lane == 0)
                __hip_atomic_store(&seq, t, __ATOMIC_RELEASE,
                                   __HIP_MEMORY_SCOPE_WORKGROUP);
        }
    } else {
        // ---- compute waves ----
        const int r0 = blockIdx.x * RPB + (wv - 1) * RPW;
        const int rr = r0 + (lane & 7);

        float wreg[RPW][16];
#pragma unroll
        for (int j = 0; j < RPW; ++j)
#pragma unroll
            for (int i = 0; i < 16; ++i)
                wreg[j][i] = whh[(size_t)(r0 + j) * HID + lane + 64 * i];

        const float cw = wgt[rr], cbi = bih[rr], cbh = bhh[rr], cb = bb[rr];
        float xw_cur = out[rr];  // xw row 0
        float dmy = 1.0f;        // busy-spin chain (kept live by asm sink)

        for (int t = 0; t < T_STEPS; ++t) {
            // spin until poller publishes step t; dummy FMAs keep VALU hot
            while (__hip_atomic_load(&seq, __ATOMIC_ACQUIRE,
                                     __HIP_MEMORY_SCOPE_WORKGROUP) < t) {
#pragma unroll
                for (int u = 0; u < 16; ++u)
                    dmy = fmaf(dmy, 1.0000001f, 1.0e-30f);
            }

            const float* hf = (const float*)(&hshw[t & 1][0]);
            float hval[16];
#pragma unroll
            for (int i = 0; i < 16; ++i) hval[i] = hf[lane + 64 * i];

            float acc[RPW];
#pragma unroll
            for (int j = 0; j < RPW; ++j) acc[j] = 0.f;
#pragma unroll
            for (int i = 0; i < 16; ++i)
#pragma unroll
                for (int j = 0; j < RPW; ++j)
                    acc[j] = fmaf(wreg[j][i], hval[i], acc[j]);

            // 3 stages x8, select own row, 3 stages x1
#pragma unroll
            for (int m = 1; m < 8; m <<= 1)
#pragma unroll
                for (int j = 0; j < RPW; ++j)
                    acc[j] += __shfl_xor(acc[j], m, 64);
            float y = acc[0];
#pragma unroll
            for (int j = 1; j < RPW; ++j) y = ((lane & 7) == j) ? acc[j] : y;
#pragma unroll
            for (int m = 8; m < 64; m <<= 1) y += __shfl_xor(y, m, 64);

            const float arg =
                fmaf(fmaf(cw, xw_cur, cbh), y, fmaf(cbi, xw_cur, cb));
            const float hn = fast_tanh(arg);
            const float hnp = __shfl_xor(hn, 1, 64);  // partner row's value

            if (lane < 8) {
                if ((lane & 1) == 0) {
                    unsigned lo = (__float_as_uint(hn) & 0xFFFFFF00u) |
                                  ((unsigned)(t + 1) & 0xFFu);
                    ull pv = ((ull)__float_as_uint(hnp) << 32) | (ull)lo;
                    __hip_atomic_store(
                        hbuf + (size_t)((t + 1) & 1) * WORDS + (r0 >> 1) +
                            (lane >> 1),
                        pv, __ATOMIC_RELAXED, __HIP_MEMORY_SCOPE_AGENT);
                }
                out[(size_t)t * HID + rr] = hn;  // off critical path
            }
            const int nt = t < T_STEPS - 1 ? t + 1 : t;
            xw_cur = out[(size_t)nt * HID + rr];  // prefetch next xw
        }
        asm volatile("" ::"v"(dmy));  // keep busy-spin chain alive (rule #17)
    }
}

extern "C" void kernel_launch(void* const* d_in, const int* in_sizes, int n_in,
                              void* d_out, int out_size, void* d_ws, size_t ws_size,
                              hipStream_t stream) {
    const float* x = (const float*)d_in[0];    // [T,1,256]
    const float* wih = (const float*)d_in[1];  // [1024,256]
    const float* whh = (const float*)d_in[2];  // [1024,1024]
    const float* wgt = (const float*)d_in[3];  // [1024]
    const float* bih = (const float*)d_in[4];
    const float* bhh = (const float*)d_in[5];
    const float* bb = (const float*)d_in[6];
    float* out = (float*)d_out;  // [T,1,1024] f32; holds xw between phases

    ull* hbuf = (ull*)d_ws;  // 2 * 512 * 8B = 8 KiB
    hipMemsetAsync(d_ws, 0, 2 * WORDS * sizeof(ull), stream);

    dim3 ggrid(HID / 128, T_STEPS / 128);
    gemm_xw<<<ggrid, 256, 0, stream>>>(x, wih, out);

    scan_rnn<<<NB, 320, 0, stream>>>(whh, wgt, bih, bhh, bb, out, hbuf);
}

// Round 6
// 92568.018 us; speedup vs baseline: 1.0782x; 1.0782x over previous
//
#include <hip/hip_runtime.h>
#include <hip/hip_bf16.h>
#include <stdint.h>

#define T_STEPS 32768
#define HID 1024
#define FIN 256
#define NBLK 16          // scan blocks
#define NWAVE 8          // waves per block (all compute; wave0 also polls)
#define RPW 8            // rows per wave
#define WORDS (HID / 2)  // packed 8B words per h vector = 512

typedef unsigned long long ull;

// ---------------- Phase 1: xw[t][h] = sum_k x[t][k] * wih[h][k] ----------------
__global__ __launch_bounds__(256) void gemm_xw(const float* __restrict__ x,
                                               const float* __restrict__ wih,
                                               float* __restrict__ out) {
    __shared__ float As[32][132];
    __shared__ float Bs[32][132];
    const int tid = threadIdx.x;
    const int m0 = blockIdx.y * 128;
    const int n0 = blockIdx.x * 128;
    const int tm = tid >> 4, tn = tid & 15;
    const int lr = tid >> 1, lc = (tid & 1) * 16;

    float acc[8][8];
#pragma unroll
    for (int i = 0; i < 8; ++i)
#pragma unroll
        for (int j = 0; j < 8; ++j) acc[i][j] = 0.f;

    for (int kk = 0; kk < FIN; kk += 32) {
#pragma unroll
        for (int u = 0; u < 4; ++u) {
            float4 av = *reinterpret_cast<const float4*>(
                &x[(size_t)(m0 + lr) * FIN + kk + lc + 4 * u]);
            float4 bv = *reinterpret_cast<const float4*>(
                &wih[(size_t)(n0 + lr) * FIN + kk + lc + 4 * u]);
            As[lc + 4 * u + 0][lr] = av.x;
            As[lc + 4 * u + 1][lr] = av.y;
            As[lc + 4 * u + 2][lr] = av.z;
            As[lc + 4 * u + 3][lr] = av.w;
            Bs[lc + 4 * u + 0][lr] = bv.x;
            Bs[lc + 4 * u + 1][lr] = bv.y;
            Bs[lc + 4 * u + 2][lr] = bv.z;
            Bs[lc + 4 * u + 3][lr] = bv.w;
        }
        __syncthreads();
#pragma unroll
        for (int k = 0; k < 32; ++k) {
            const float4* Ak = reinterpret_cast<const float4*>(&As[k][0]);
            const float4* Bk = reinterpret_cast<const float4*>(&Bs[k][0]);
            float4 a0 = Ak[tm * 2], a1 = Ak[tm * 2 + 1];
            float4 b0 = Bk[tn * 2], b1 = Bk[tn * 2 + 1];
            float a[8] = {a0.x, a0.y, a0.z, a0.w, a1.x, a1.y, a1.z, a1.w};
            float b[8] = {b0.x, b0.y, b0.z, b0.w, b1.x, b1.y, b1.z, b1.w};
#pragma unroll
            for (int i = 0; i < 8; ++i)
#pragma unroll
                for (int j = 0; j < 8; ++j) acc[i][j] = fmaf(a[i], b[j], acc[i][j]);
        }
        __syncthreads();
    }
#pragma unroll
    for (int i = 0; i < 8; ++i) {
        float4 o0 = make_float4(acc[i][0], acc[i][1], acc[i][2], acc[i][3]);
        float4 o1 = make_float4(acc[i][4], acc[i][5], acc[i][6], acc[i][7]);
        float* op = &out[(size_t)(m0 + tm * 8 + i) * HID + n0 + tn * 8];
        *reinterpret_cast<float4*>(op) = o0;
        *reinterpret_cast<float4*>(op + 4) = o1;
    }
}

// ---------------- Phase 2: persistent serial scan ----------------
__device__ __forceinline__ float fast_tanh(float x) {
    float cx = fminf(fmaxf(x, -16.f), 16.f);
    float e = __builtin_amdgcn_exp2f(cx * 2.8853900817779268f);
    return (e - 1.f) * __builtin_amdgcn_rcpf(e + 1.f);
}

// Split detect/data transport:
//  * data: 2 parity buffers x 512 packed words (2 x f32, FULL precision, no
//    tag bits). Written once per step (relaxed agent atomics), read ONCE per
//    step per block by wave0 after detect -> data lines are never polled, so
//    producer stores don't queue behind a read storm (R0-R5 evidence: time
//    tracked poll pressure on the store-target lines).
//  * detect: done[16] ints on ONE 64B line. Producer protocol per wave:
//    packed h stores -> s_waitcnt vmcnt(0) (per-WAVE, covers all lanes'
//    stores at agent scope) -> barrier(B) -> wave0-lane0 stores
//    done[blk]=t+1. Consumer: wave0 acquire-polls done[lane&15] with
//    s_sleep(1) between misses (sleep helped in R2-kernel, best so far).
//  * 16 blocks x 8 waves: fewer producers to converge + fewer pollers.
// Safety: done[b]>=t for all b implies every block passed barrier(B) of
// step t-1, hence all reads of data buf[(t+1)&1] (done at step t-1) and all
// LDS reads of step t-1 are complete -> single LDS buffer + parity data
// buffers are race-free. done is monotonic (no ABA).
__global__ __launch_bounds__(512, 1) void scan_rnn(
    const float* __restrict__ whh, const float* __restrict__ wgt,
    const float* __restrict__ bih, const float* __restrict__ bhh,
    const float* __restrict__ bb, float* __restrict__ out,
    ull* __restrict__ hbuf, int* __restrict__ done) {
    __shared__ ull hshw[WORDS];
    const int lane = threadIdx.x & 63;
    const int wv = threadIdx.x >> 6;
    const int r0 = blockIdx.x * (NWAVE * RPW) + wv * RPW;
    const int rr = r0 + (lane & 7);

    // W_hh slice: lane covers k = lane + 64*i
    float wreg[RPW][16];
#pragma unroll
    for (int j = 0; j < RPW; ++j)
#pragma unroll
        for (int i = 0; i < 16; ++i)
            wreg[j][i] = whh[(size_t)(r0 + j) * HID + lane + 64 * i];

    const float cw = wgt[rr], cbi = bih[rr], cbh = bhh[rr], cb = bb[rr];
    float xw_cur = out[rr];  // xw row 0 (scan launches after gemm)

    for (int t = 0; t < T_STEPS; ++t) {
        if (wv == 0) {
            // ---- detect: poll the single done-line ----
            int v = __hip_atomic_load(&done[lane & 15], __ATOMIC_ACQUIRE,
                                      __HIP_MEMORY_SCOPE_AGENT);
            while (!__all(v >= t)) {
                __builtin_amdgcn_s_sleep(1);
                v = __hip_atomic_load(&done[lane & 15], __ATOMIC_ACQUIRE,
                                      __HIP_MEMORY_SCOPE_AGENT);
            }
            // ---- data: one-shot fetch, publish to LDS ----
            const ull* src = hbuf + (size_t)(t & 1) * WORDS;
            ull dv[8];
#pragma unroll
            for (int i = 0; i < 8; ++i)
                dv[i] = __hip_atomic_load(src + lane + 64 * i, __ATOMIC_RELAXED,
                                          __HIP_MEMORY_SCOPE_AGENT);
#pragma unroll
            for (int i = 0; i < 8; ++i) hshw[lane + 64 * i] = dv[i];
        }
        __syncthreads();  // (A) h_t available in LDS

        const float* hf = (const float*)(&hshw[0]);
        float hval[16];
#pragma unroll
        for (int i = 0; i < 16; ++i) hval[i] = hf[lane + 64 * i];

        float acc[RPW];
#pragma unroll
        for (int j = 0; j < RPW; ++j) acc[j] = 0.f;
#pragma unroll
        for (int i = 0; i < 16; ++i)
#pragma unroll
            for (int j = 0; j < RPW; ++j)
                acc[j] = fmaf(wreg[j][i], hval[i], acc[j]);

        // 3 stages x8, select own row, 3 stages x1
#pragma unroll
        for (int m = 1; m < 8; m <<= 1)
#pragma unroll
            for (int j = 0; j < RPW; ++j) acc[j] += __shfl_xor(acc[j], m, 64);
        float y = acc[0];
#pragma unroll
        for (int j = 1; j < RPW; ++j) y = ((lane & 7) == j) ? acc[j] : y;
#pragma unroll
        for (int m = 8; m < 64; m <<= 1) y += __shfl_xor(y, m, 64);

        const float arg = fmaf(fmaf(cw, xw_cur, cbh), y, fmaf(cbi, xw_cur, cb));
        const float hn = fast_tanh(arg);
        const float hnp = __shfl_xor(hn, 1, 64);  // partner (odd) row's value

        // publish h_{t+1}: full-precision pack, data lines unpolled
        if ((lane & 9) == 0 && lane < 8) {  // lanes 0,2,4,6
        }
        if (lane < 8 && (lane & 1) == 0) {
            ull pv = ((ull)__float_as_uint(hnp) << 32) |
                     (ull)__float_as_uint(hn);
            __hip_atomic_store(
                hbuf + (size_t)((t + 1) & 1) * WORDS + (r0 >> 1) + (lane >> 1),
                pv, __ATOMIC_RELAXED, __HIP_MEMORY_SCOPE_AGENT);
        }
        // per-wave fence: all lanes' packed stores acked at coherence point
        asm volatile("s_waitcnt vmcnt(0)" ::: "memory");
        if (lane < 8) out[(size_t)t * HID + rr] = hn;  // off critical path
        __syncthreads();  // (B) all waves of this block fenced
        if (wv == 0 && lane == 0)
            __hip_atomic_store(&done[blockIdx.x], t + 1, __ATOMIC_RELAXED,
                               __HIP_MEMORY_SCOPE_AGENT);
        // prefetch next xw AFTER the fence (never stalls the fence; HBM
        // latency hides under the inter-step wait)
        const int nt = t < T_STEPS - 1 ? t + 1 : t;
        xw_cur = out[(size_t)nt * HID + rr];
    }
}

extern "C" void kernel_launch(void* const* d_in, const int* in_sizes, int n_in,
                              void* d_out, int out_size, void* d_ws, size_t ws_size,
                              hipStream_t stream) {
    const float* x = (const float*)d_in[0];    // [T,1,256]
    const float* wih = (const float*)d_in[1];  // [1024,256]
    const float* whh = (const float*)d_in[2];  // [1024,1024]
    const float* wgt = (const float*)d_in[3];  // [1024]
    const float* bih = (const float*)d_in[4];
    const float* bhh = (const float*)d_in[5];
    const float* bb = (const float*)d_in[6];
    float* out = (float*)d_out;  // [T,1,1024] f32; holds xw between phases

    ull* hbuf = (ull*)d_ws;                        // 2*512*8B = 8 KiB data
    int* done = (int*)((char*)d_ws + 2 * WORDS * sizeof(ull));  // 16 ints
    hipMemsetAsync(d_ws, 0, 2 * WORDS * sizeof(ull) + 128, stream);

    dim3 ggrid(HID / 128, T_STEPS / 128);
    gemm_xw<<<ggrid, 256, 0, stream>>>(x, wih, out);

    scan_rnn<<<NBLK, 512, 0, stream>>>(whh, wgt, bih, bhh, bb, out, hbuf, done);
}

// Round 7
// 62550.903 us; speedup vs baseline: 1.5956x; 1.4799x over previous
//
#include <hip/hip_runtime.h>
#include <hip/hip_bf16.h>
#include <stdint.h>

#define T_STEPS 32768
#define HID 1024
#define FIN 256
#define NB_SCAN 32       // scan blocks
#define NB_HEAT 8        // clock-heater blocks (~1 per XCD)
#define RPB 32           // rows per scan block
#define RPW 8            // rows per wave (4 waves/block)
#define WORDS (HID / 2)  // packed 8B words per h vector = 512

typedef unsigned long long ull;

// ---------------- Phase 1: xw[t][h] = sum_k x[t][k] * wih[h][k] ----------------
__global__ __launch_bounds__(256) void gemm_xw(const float* __restrict__ x,
                                               const float* __restrict__ wih,
                                               float* __restrict__ out) {
    __shared__ float As[32][132];
    __shared__ float Bs[32][132];
    const int tid = threadIdx.x;
    const int m0 = blockIdx.y * 128;
    const int n0 = blockIdx.x * 128;
    const int tm = tid >> 4, tn = tid & 15;
    const int lr = tid >> 1, lc = (tid & 1) * 16;

    float acc[8][8];
#pragma unroll
    for (int i = 0; i < 8; ++i)
#pragma unroll
        for (int j = 0; j < 8; ++j) acc[i][j] = 0.f;

    for (int kk = 0; kk < FIN; kk += 32) {
#pragma unroll
        for (int u = 0; u < 4; ++u) {
            float4 av = *reinterpret_cast<const float4*>(
                &x[(size_t)(m0 + lr) * FIN + kk + lc + 4 * u]);
            float4 bv = *reinterpret_cast<const float4*>(
                &wih[(size_t)(n0 + lr) * FIN + kk + lc + 4 * u]);
            As[lc + 4 * u + 0][lr] = av.x;
            As[lc + 4 * u + 1][lr] = av.y;
            As[lc + 4 * u + 2][lr] = av.z;
            As[lc + 4 * u + 3][lr] = av.w;
            Bs[lc + 4 * u + 0][lr] = bv.x;
            Bs[lc + 4 * u + 1][lr] = bv.y;
            Bs[lc + 4 * u + 2][lr] = bv.z;
            Bs[lc + 4 * u + 3][lr] = bv.w;
        }
        __syncthreads();
#pragma unroll
        for (int k = 0; k < 32; ++k) {
            const float4* Ak = reinterpret_cast<const float4*>(&As[k][0]);
            const float4* Bk = reinterpret_cast<const float4*>(&Bs[k][0]);
            float4 a0 = Ak[tm * 2], a1 = Ak[tm * 2 + 1];
            float4 b0 = Bk[tn * 2], b1 = Bk[tn * 2 + 1];
            float a[8] = {a0.x, a0.y, a0.z, a0.w, a1.x, a1.y, a1.z, a1.w};
            float b[8] = {b0.x, b0.y, b0.z, b0.w, b1.x, b1.y, b1.z, b1.w};
#pragma unroll
            for (int i = 0; i < 8; ++i)
#pragma unroll
                for (int j = 0; j < 8; ++j) acc[i][j] = fmaf(a[i], b[j], acc[i][j]);
        }
        __syncthreads();
    }
#pragma unroll
    for (int i = 0; i < 8; ++i) {
        float4 o0 = make_float4(acc[i][0], acc[i][1], acc[i][2], acc[i][3]);
        float4 o1 = make_float4(acc[i][4], acc[i][5], acc[i][6], acc[i][7]);
        float* op = &out[(size_t)(m0 + tm * 8 + i) * HID + n0 + tn * 8];
        *reinterpret_cast<float4*>(op) = o0;
        *reinterpret_cast<float4*>(op + 4) = o1;
    }
}

// ---------------- Phase 2: persistent serial scan + clock heaters ----------------
__device__ __forceinline__ float fast_tanh(float x) {
    float cx = fminf(fmaxf(x, -16.f), 16.f);
    float e = __builtin_amdgcn_exp2f(cx * 2.8853900817779268f);
    return (e - 1.f) * __builtin_amdgcn_rcpf(e + 1.f);
}

__device__ __forceinline__ void poll8(const ull* __restrict__ src, int lane,
                                      ull (&v)[8]) {
#pragma unroll
    for (int i = 0; i < 8; ++i)
        v[i] = __hip_atomic_load(src + lane + 64 * i, __ATOMIC_RELAXED,
                                 __HIP_MEMORY_SCOPE_AGENT);
}

__device__ __forceinline__ bool check8(const ull (&v)[8], unsigned expb) {
    unsigned d = 0;
#pragma unroll
    for (int i = 0; i < 8; ++i) d |= (((unsigned)v[i]) ^ expb) & 0xFFu;
    return d == 0;
}

// Heater: dense independent FMAs (SCLK) + light strided HBM reads (FCLK/MCLK),
// on CUs that don't run scan blocks. Polls quit flag every ~0.4 us.
__device__ void heater_body(const int* quit, const float* __restrict__ mem,
                            int bi, int tid) {
    float a0 = tid * 0.001f + 1.f, a1 = a0 + 1.f, a2 = a0 + 2.f, a3 = a0 + 3.f;
    float a4 = a0 + 4.f, a5 = a0 + 5.f, a6 = a0 + 6.f, a7 = a0 + 7.f;
    // stride through the 32M-float out buffer (128 MB > MALL -> real HBM reads)
    size_t idx = ((size_t)bi * 256 + tid) * 4;
    const size_t mask = (32u * 1024u * 1024u) - 1u;
    for (;;) {
        float4 v = *reinterpret_cast<const float4*>(&mem[idx & mask & ~3ull]);
        a0 = fmaf(v.x, 1e-30f, a0);
#pragma unroll 64
        for (int u = 0; u < 64; ++u) {
            a0 = fmaf(a0, 1.0000001f, 0.5f);
            a1 = fmaf(a1, 1.0000001f, 0.5f);
            a2 = fmaf(a2, 1.0000001f, 0.5f);
            a3 = fmaf(a3, 1.0000001f, 0.5f);
            a4 = fmaf(a4, 1.0000001f, 0.5f);
            a5 = fmaf(a5, 1.0000001f, 0.5f);
            a6 = fmaf(a6, 1.0000001f, 0.5f);
            a7 = fmaf(a7, 1.0000001f, 0.5f);
        }
        idx += 64 * 2048;
        if (__hip_atomic_load(quit, __ATOMIC_RELAXED, __HIP_MEMORY_SCOPE_AGENT))
            break;
    }
    asm volatile("" ::"v"(a0), "v"(a1), "v"(a2), "v"(a3), "v"(a4), "v"(a5),
                 "v"(a6), "v"(a7));
}

// Transport (R3 protocol, best so far, + R4 packing):
//  h packed as 512 x 8B words (two f32); even element's low mantissa byte =
//  tag (t+1)&0xFF (perturbation 2^-16 rel; stale generation differs by 2 mod
//  256 -> never collides). Double-buffered by parity, relaxed agent atomics.
//  Per block: wave0 dual-role -- polls all 512 words (8/lane, 2-deep
//  pipeline, s_sleep(1) after both refills), publishes packed words to LDS,
//  one __syncthreads, then computes its 8 rows like waves 1-3.
//  Single-barrier safety: wave0 overwrites hshw for step t only after ALL
//  512 tags==t, which requires this block's own h_t stores, which each wave
//  issues only after reading all its hval from hshw (step t-1) -> no overlap.
__global__ __launch_bounds__(256, 1) void scan_rnn(
    const float* __restrict__ whh, const float* __restrict__ wgt,
    const float* __restrict__ bih, const float* __restrict__ bhh,
    const float* __restrict__ bb, float* __restrict__ out,
    ull* __restrict__ hbuf, int* __restrict__ quit) {
    if (blockIdx.x >= NB_SCAN) {
        heater_body(quit, out, blockIdx.x - NB_SCAN, threadIdx.x);
        return;
    }
    __shared__ ull hshw[WORDS];
    const int lane = threadIdx.x & 63;
    const int wv = threadIdx.x >> 6;
    const int r0 = blockIdx.x * RPB + wv * RPW;
    const int rr = r0 + (lane & 7);

    // W_hh slice: lane covers k = lane + 64*i
    float wreg[RPW][16];
#pragma unroll
    for (int j = 0; j < RPW; ++j)
#pragma unroll
        for (int i = 0; i < 16; ++i)
            wreg[j][i] = whh[(size_t)(r0 + j) * HID + lane + 64 * i];

    const float cw = wgt[rr], cbi = bih[rr], cbh = bhh[rr], cb = bb[rr];
    float xw_cur = out[rr];  // xw row 0 (scan launches after gemm)

    for (int t = 0; t < T_STEPS; ++t) {
        if (wv == 0) {
            // tag-in-data poll: detect == data, no extra RT
            const ull* src = hbuf + (size_t)(t & 1) * WORDS;
            const unsigned expb = (unsigned)t & 0xFFu;
            ull va[8], vb[8];
            poll8(src, lane, va);
            for (;;) {
                poll8(src, lane, vb);
                if (check8(va, expb)) {
#pragma unroll
                    for (int i = 0; i < 8; ++i) hshw[lane + 64 * i] = va[i];
                    break;
                }
                poll8(src, lane, va);
                if (check8(vb, expb)) {
#pragma unroll
                    for (int i = 0; i < 8; ++i) hshw[lane + 64 * i] = vb[i];
                    break;
                }
                __builtin_amdgcn_s_sleep(1);
            }
        }
        __syncthreads();  // h_t available in LDS (packed words == f32[1024])

        const float* hf = (const float*)(&hshw[0]);
        float hval[16];
#pragma unroll
        for (int i = 0; i < 16; ++i) hval[i] = hf[lane + 64 * i];

        float acc[RPW];
#pragma unroll
        for (int j = 0; j < RPW; ++j) acc[j] = 0.f;
#pragma unroll
        for (int i = 0; i < 16; ++i)
#pragma unroll
            for (int j = 0; j < RPW; ++j)
                acc[j] = fmaf(wreg[j][i], hval[i], acc[j]);

        // 3 stages x8, select own row, 3 stages x1
#pragma unroll
        for (int m = 1; m < 8; m <<= 1)
#pragma unroll
            for (int j = 0; j < RPW; ++j) acc[j] += __shfl_xor(acc[j], m, 64);
        float y = acc[0];
#pragma unroll
        for (int j = 1; j < RPW; ++j) y = ((lane & 7) == j) ? acc[j] : y;
#pragma unroll
        for (int m = 8; m < 64; m <<= 1) y += __shfl_xor(y, m, 64);

        const float arg = fmaf(fmaf(cw, xw_cur, cbh), y, fmaf(cbi, xw_cur, cb));
        const float hn = fast_tanh(arg);
        const float hnp = __shfl_xor(hn, 1, 64);  // partner (odd) row's value

        if (lane < 8) {
            if ((lane & 1) == 0) {
                // tagged packed store FIRST (critical path)
                unsigned lo = (__float_as_uint(hn) & 0xFFFFFF00u) |
                              ((unsigned)(t + 1) & 0xFFu);
                ull pv = ((ull)__float_as_uint(hnp) << 32) | (ull)lo;
                __hip_atomic_store(
                    hbuf + (size_t)((t + 1) & 1) * WORDS + (r0 >> 1) +
                        (lane >> 1),
                    pv, __ATOMIC_RELAXED, __HIP_MEMORY_SCOPE_AGENT);
            }
            out[(size_t)t * HID + rr] = hn;  // result store, off critical path
        }
        // prefetch next xw; HBM latency hides under inter-step wait
        const int nt = t < T_STEPS - 1 ? t + 1 : t;
        xw_cur = out[(size_t)nt * HID + rr];
    }
    if (blockIdx.x == 0 && threadIdx.x == 0)
        __hip_atomic_store(quit, 1, __ATOMIC_RELAXED, __HIP_MEMORY_SCOPE_AGENT);
}

extern "C" void kernel_launch(void* const* d_in, const int* in_sizes, int n_in,
                              void* d_out, int out_size, void* d_ws, size_t ws_size,
                              hipStream_t stream) {
    const float* x = (const float*)d_in[0];    // [T,1,256]
    const float* wih = (const float*)d_in[1];  // [1024,256]
    const float* whh = (const float*)d_in[2];  // [1024,1024]
    const float* wgt = (const float*)d_in[3];  // [1024]
    const float* bih = (const float*)d_in[4];
    const float* bhh = (const float*)d_in[5];
    const float* bb = (const float*)d_in[6];
    float* out = (float*)d_out;  // [T,1,1024] f32; holds xw between phases

    ull* hbuf = (ull*)d_ws;  // 2*512*8B = 8 KiB
    int* quit = (int*)((char*)d_ws + 2 * WORDS * sizeof(ull));
    hipMemsetAsync(d_ws, 0, 2 * WORDS * sizeof(ull) + 128, stream);

    dim3 ggrid(HID / 128, T_STEPS / 128);
    gemm_xw<<<ggrid, 256, 0, stream>>>(x, wih, out);

    scan_rnn<<<NB_SCAN + NB_HEAT, 256, 0, stream>>>(whh, wgt, bih, bhh, bb,
                                                    out, hbuf, quit);
}